// Round 2
// baseline (294.355 us; speedup 1.0000x reference)
//
#include <hip/hip_runtime.h>
#include <math.h>

#define LL 2048
#define DD 128
#define NS 16                          // 2 sources * 8 batches
#define SLAB (LL * DD)                 // 262144 elements per (src,n)
#define SCALE 0.08838834764831845f     // 1/sqrt(128)
#define NT 16                          // 128-row tiles per slab
#define NPAIR 136                      // NT*(NT+1)/2 upper-triangle pairs

typedef __attribute__((ext_vector_type(8))) short short8v;   // 8 bf16 (4 VGPR)
typedef __attribute__((ext_vector_type(4))) float float4v;   // MFMA C/D

__device__ __forceinline__ unsigned int f2bf(float f) {   // RNE, low 16 bits
    unsigned int u = __float_as_uint(f);
    u += 0x7fffu + ((u >> 16) & 1u);
    return u >> 16;
}
__device__ __forceinline__ void pair_decode(int p, int& ib, int& jb) {
    int i = 0;
    while (p >= NT - i) { p -= NT - i; ++i; }
    ib = i; jb = i + p;
}

// async global->LDS, 16B per lane; LDS dest = wave-uniform base + lane*16
__device__ __forceinline__ void gl_lds16(const void* g, void* l) {
    __builtin_amdgcn_global_load_lds(
        (const __attribute__((address_space(1))) void*)g,
        (__attribute__((address_space(3))) void*)l, 16, 0, 0);
}

// Stage one 128x32 bf16 chunk of tile gT (already offset to kc*32 cols) into
// panel-layout lbuf: slot c in [0,512): q=c>>7, row=c&127;
// LDS[c*16B] = gT[row*DD + q*8 .. +8]. Frag reads of (row, q=quad) then hit
// 16 consecutive 16B slots per 16-lane group -> conflict-free ds_read_b128.
__device__ __forceinline__ void stage_tile(
    const unsigned short* __restrict__ gT, unsigned short* lbuf, int tid)
{
#pragma unroll
    for (int it = 0; it < 2; ++it) {
        const int c  = tid + it * 256;
        const int cb = (tid & ~63) + it * 256;            // wave-uniform base slot
        gl_lds16(gT + (size_t)(c & 127) * DD + (c >> 7) * 8, lbuf + cb * 8);
    }
}

// ---------------------------------------------------------------------------
// Kernel 1: P = x @ W^T + b (fp32), split to P_hi/P_lo bf16 in d_out.
// Block: 64 l-rows x 128 d. Grid: (32 l-tiles, 16 ns) = 512 blocks.
// ---------------------------------------------------------------------------
__global__ __launch_bounds__(256, 4) void proj_kernel(
    const float* __restrict__ xt, const float* __restrict__ xf,
    const float* __restrict__ W,  const float* __restrict__ bias,
    unsigned short* __restrict__ Ph, unsigned short* __restrict__ Pl)
{
    __shared__ float Alds[64 * 36];
    __shared__ float Blds[128 * 36];
    __shared__ float bs[128];
    const int ns = blockIdx.y;
    const int l0 = blockIdx.x * 64;
    const int src = ns >> 3, n = ns & 7;
    const float* x = (src ? xf : xt) + (size_t)n * LL * DD;
    const int tid = threadIdx.x;
    const int ty = tid >> 4, tx = tid & 15;

    if (tid < 128) bs[tid] = bias[tid];
    __syncthreads();

    float acc[4][8];
#pragma unroll
    for (int i = 0; i < 4; ++i)
#pragma unroll
        for (int j = 0; j < 8; ++j) acc[i][j] = bs[tx + 16 * j];

    for (int kc = 0; kc < 4; ++kc) {
        __syncthreads();
#pragma unroll
        for (int t = 0; t < 2; ++t) {            // x: 64 x 32 = 512 float4
            int idx = tid + t * 256;
            int r = idx >> 3, k4 = (idx & 7) << 2;
            *(float4*)&Alds[r * 36 + k4] =
                *(const float4*)&x[(size_t)(l0 + r) * DD + kc * 32 + k4];
        }
#pragma unroll
        for (int t = 0; t < 4; ++t) {            // W: 128 x 32 = 1024 float4
            int idx = tid + t * 256;
            int r = idx >> 3, k4 = (idx & 7) << 2;
            *(float4*)&Blds[r * 36 + k4] =
                *(const float4*)&W[(size_t)r * DD + kc * 32 + k4];
        }
        __syncthreads();
#pragma unroll
        for (int k4 = 0; k4 < 32; k4 += 4) {
            float4 a4[4], b4[8];
#pragma unroll
            for (int i = 0; i < 4; ++i) a4[i] = *(const float4*)&Alds[(ty + 16 * i) * 36 + k4];
#pragma unroll
            for (int j = 0; j < 8; ++j) b4[j] = *(const float4*)&Blds[(tx + 16 * j) * 36 + k4];
#pragma unroll
            for (int i = 0; i < 4; ++i)
#pragma unroll
                for (int j = 0; j < 8; ++j) {
                    acc[i][j] = fmaf(a4[i].x, b4[j].x, acc[i][j]);
                    acc[i][j] = fmaf(a4[i].y, b4[j].y, acc[i][j]);
                    acc[i][j] = fmaf(a4[i].z, b4[j].z, acc[i][j]);
                    acc[i][j] = fmaf(a4[i].w, b4[j].w, acc[i][j]);
                }
        }
    }
#pragma unroll
    for (int i = 0; i < 4; ++i) {
        const size_t rowo = (size_t)ns * SLAB + (size_t)(l0 + ty + 16 * i) * DD;
#pragma unroll
        for (int j = 0; j < 8; ++j) {
            float p = acc[i][j];
            unsigned int hb = f2bf(p);
            float hf = __uint_as_float(hb << 16);
            unsigned int lb = f2bf(p - hf);
            Ph[rowo + tx + 16 * j] = (unsigned short)hb;
            Pl[rowo + tx + 16 * j] = (unsigned short)lb;
        }
    }
}

// ---------------------------------------------------------------------------
// MFMA bf16x3 GEMM core v3 (hi*hi + hi*lo + lo*hi).
// 4 waves in 2x2 grid; each wave owns a 64x64 quadrant of S(ib,jb).
//   - BOTH A and B staged via global_load_lds into conflict-free panel
//     layout, single-buffered, 2 barriers per kc (R1 lesson: A direct from
//     global exposed ~500cyc L2/L3 latency per kc on the MFMA critical path;
//     ds_read ~120cyc + 2x inter-wave reuse wins).
//   - diag pairs (ib==jb) alias B panels to A panels (half the staging).
// acc frag (16x16x32): out row = quad*4 + reg, out col = l16.
// ---------------------------------------------------------------------------
__device__ __forceinline__ void mfma_core(
    const unsigned short* __restrict__ Ph, const unsigned short* __restrict__ Pl,
    int ns, int ib, int jb, int tid,
    unsigned short* Ah, unsigned short* Al,
    unsigned short* Bh, unsigned short* Bl,
    float4v (&acc)[4][4])
{
    const int lane = tid & 63;
    const int quad = lane >> 4, l16 = lane & 15;
    const int wave = tid >> 6;
    const int wr = wave >> 1, wc = wave & 1;
    const bool dg = (ib == jb);

    const unsigned short* sAh = Ph + (size_t)ns * SLAB + (size_t)ib * 128 * DD;
    const unsigned short* sAl = Pl + (size_t)ns * SLAB + (size_t)ib * 128 * DD;
    const unsigned short* sBh = Ph + (size_t)ns * SLAB + (size_t)jb * 128 * DD;
    const unsigned short* sBl = Pl + (size_t)ns * SLAB + (size_t)jb * 128 * DD;
    const unsigned short* pBh = dg ? Ah : Bh;
    const unsigned short* pBl = dg ? Al : Bl;

#pragma unroll
    for (int i = 0; i < 4; ++i)
#pragma unroll
        for (int j = 0; j < 4; ++j)
#pragma unroll
            for (int r = 0; r < 4; ++r) acc[i][j][r] = 0.f;

#pragma unroll
    for (int kc = 0; kc < 4; ++kc) {
        if (kc) __syncthreads();             // all waves done reading prev kc
        stage_tile(sAh + kc * 32, Ah, tid);
        stage_tile(sAl + kc * 32, Al, tid);
        if (!dg) {
            stage_tile(sBh + kc * 32, Bh, tid);
            stage_tile(sBl + kc * 32, Bl, tid);
        }
        __syncthreads();                     // compiler drains vmcnt(0) here

        short8v ah[4], al[4], bh[4], bl[4];
#pragma unroll
        for (int rt = 0; rt < 4; ++rt) {
            const int off = (quad * 128 + wr * 64 + rt * 16 + l16) * 8;
            ah[rt] = *(const short8v*)&Ah[off];
            al[rt] = *(const short8v*)&Al[off];
        }
#pragma unroll
        for (int ct = 0; ct < 4; ++ct) {
            const int off = (quad * 128 + wc * 64 + ct * 16 + l16) * 8;
            bh[ct] = *(const short8v*)&pBh[off];
            bl[ct] = *(const short8v*)&pBl[off];
        }
#pragma unroll
        for (int rt = 0; rt < 4; ++rt)
#pragma unroll
            for (int ct = 0; ct < 4; ++ct) {
                acc[rt][ct] = __builtin_amdgcn_mfma_f32_16x16x32_bf16(ah[rt], bh[ct], acc[rt][ct], 0, 0, 0);
                acc[rt][ct] = __builtin_amdgcn_mfma_f32_16x16x32_bf16(ah[rt], bl[ct], acc[rt][ct], 0, 0, 0);
                acc[rt][ct] = __builtin_amdgcn_mfma_f32_16x16x32_bf16(al[rt], bh[ct], acc[rt][ct], 0, 0, 0);
            }
    }
}

// XCD-aware pair swizzle: 136 pairs = 8 XCDs * 17. Each XCD gets 17
// consecutive pairs of the same ns -> per-XCD L2 working set ~2MB (fits 4MB).
__device__ __forceinline__ int pair_swz(int x) {
    return (x & 7) * 17 + (x >> 3);
}

// ---------------------------------------------------------------------------
// Kernel 2: per tile-pair UNSHIFTED softmax denominators: Zpart row sums of
// exp(s) for rows of BOTH blocks. Zpart: [(ns*16 + othertile)*2048 + row]
// ---------------------------------------------------------------------------
__global__ __launch_bounds__(256, 4) void stats_kernel(
    const unsigned short* __restrict__ Ph, const unsigned short* __restrict__ Pl,
    float* __restrict__ Zpart)
{
    __shared__ unsigned short Ah[4096], Al[4096], Bh[4096], Bl[4096];   // 32 KB
    __shared__ float Zr[128][2], Zc[128][2];                            // 2 KB
    int ib, jb;  pair_decode(pair_swz(blockIdx.x), ib, jb);
    const int ns = blockIdx.y;
    const int tid = threadIdx.x;
    const int lane = tid & 63, quad = lane >> 4, l16 = lane & 15, wave = tid >> 6;
    const int wr = wave >> 1, wc = wave & 1;

    float4v acc[4][4];
    mfma_core(Ph, Pl, ns, ib, jb, tid, Ah, Al, Bh, Bl, acc);

    float cs[4] = {0.f, 0.f, 0.f, 0.f};
#pragma unroll
    for (int rt = 0; rt < 4; ++rt)
#pragma unroll
        for (int rg = 0; rg < 4; ++rg) {
            float e[4];
            float s = 0.f;
#pragma unroll
            for (int ct = 0; ct < 4; ++ct) {
                e[ct] = __expf(acc[rt][ct][rg] * SCALE);
                s += e[ct]; cs[ct] += e[ct];
            }
            s += __shfl_xor(s, 1);
            s += __shfl_xor(s, 2);
            s += __shfl_xor(s, 4);
            s += __shfl_xor(s, 8);
            if (l16 == 0) Zr[wr * 64 + rt * 16 + quad * 4 + rg][wc] = s;
        }

    // transpose partials: sums over this wave's 64 rows for its 64 cols
#pragma unroll
    for (int ct = 0; ct < 4; ++ct) {
        float s = cs[ct];
        s += __shfl_xor(s, 16);
        s += __shfl_xor(s, 32);
        if (quad == 0) Zc[wc * 64 + ct * 16 + l16][wr] = s;
    }
    __syncthreads();
    if (tid < 128) {
        Zpart[(ns * 16 + jb) * LL + ib * 128 + tid] = Zr[tid][0] + Zr[tid][1];
        if (ib != jb)
            Zpart[(ns * 16 + ib) * LL + jb * 128 + tid] = Zc[tid][0] + Zc[tid][1];
    }
}

// ---------------------------------------------------------------------------
// Kernel 3: iZ[row] = 1 / sum of 16 per-tile partials
// ---------------------------------------------------------------------------
__global__ __launch_bounds__(256) void reduce_stats_kernel(
    const float* __restrict__ Zpart, float* __restrict__ iZfin)
{
    const int idx = blockIdx.x * 256 + threadIdx.x;   // ns*2048 + l
    const int ns = idx >> 11, l = idx & 2047;
    float Z = 0.f;
#pragma unroll
    for (int t = 0; t < 16; ++t) Z += Zpart[(ns * 16 + t) * LL + l];
    iZfin[idx] = 1.0f / Z;
}

// ---------------------------------------------------------------------------
// Kernel 4: recompute s (identical MFMA sequence), per-tile column partial
// sums of exp(s)*iZ_row for cols of BOTH blocks. Spart: [(ns*2048+m)*16+tile]
// ---------------------------------------------------------------------------
__global__ __launch_bounds__(256, 4) void colsum_kernel(
    const unsigned short* __restrict__ Ph, const unsigned short* __restrict__ Pl,
    const float* __restrict__ iZfin, float* __restrict__ Spart)
{
    __shared__ unsigned short Ah[4096], Al[4096], Bh[4096], Bl[4096];   // 32 KB
    __shared__ float Sr[128][2], Sc[128][2];                            // 2 KB
    int ib, jb;  pair_decode(pair_swz(blockIdx.x), ib, jb);
    const int ns = blockIdx.y;
    const int tid = threadIdx.x;
    const int lane = tid & 63, quad = lane >> 4, l16 = lane & 15, wave = tid >> 6;
    const int wr = wave >> 1, wc = wave & 1;

    float4v acc[4][4];
    mfma_core(Ph, Pl, ns, ib, jb, tid, Ah, Al, Bh, Bl, acc);

    float wrow[4][4];
#pragma unroll
    for (int rt = 0; rt < 4; ++rt)
#pragma unroll
        for (int rg = 0; rg < 4; ++rg)
            wrow[rt][rg] = iZfin[ns * LL + ib * 128 + wr * 64 + rt * 16 + quad * 4 + rg];
    float wcol[4];
#pragma unroll
    for (int ct = 0; ct < 4; ++ct)
        wcol[ct] = iZfin[ns * LL + jb * 128 + wc * 64 + ct * 16 + l16];

    float dsum[4] = {0.f, 0.f, 0.f, 0.f};
#pragma unroll
    for (int rt = 0; rt < 4; ++rt)
#pragma unroll
        for (int rg = 0; rg < 4; ++rg) {
            const int rl = wr * 64 + rt * 16 + quad * 4 + rg;
            float ts = 0.f;
#pragma unroll
            for (int ct = 0; ct < 4; ++ct) {
                float e = __expf(acc[rt][ct][rg] * SCALE);
                bool diag = (ib == jb) && (rl == wc * 64 + ct * 16 + l16);
                dsum[ct] += diag ? 0.f : e * wrow[rt][rg];
                ts += e * wcol[ct];
            }
            if (ib != jb) {
                ts += __shfl_xor(ts, 1);
                ts += __shfl_xor(ts, 2);
                ts += __shfl_xor(ts, 4);
                ts += __shfl_xor(ts, 8);
                if (l16 == 0) Sr[rl][wc] = ts;
            }
        }

#pragma unroll
    for (int ct = 0; ct < 4; ++ct) {
        float s = dsum[ct];
        s += __shfl_xor(s, 16);
        s += __shfl_xor(s, 32);
        if (quad == 0) Sc[wc * 64 + ct * 16 + l16][wr] = s;
    }
    __syncthreads();
    if (tid < 128) {
        Spart[((size_t)ns * LL + jb * 128 + tid) * 16 + ib] = Sc[tid][0] + Sc[tid][1];
        if (ib != jb)
            Spart[((size_t)ns * LL + ib * 128 + tid) * 16 + jb] = Sr[tid][0] + Sr[tid][1];
    }
}

// ---------------------------------------------------------------------------
// Kernel 5: score = fp64 sum of 16 tile partials; exact bottom-k mask via
// rank counting: mask[i] = #{j: score_j < score_i} < 1024
// ---------------------------------------------------------------------------
__global__ __launch_bounds__(1024) void mask_kernel(
    const float* __restrict__ Spart, unsigned char* __restrict__ maskbuf)
{
    __shared__ double s[LL];
    const int ns = blockIdx.x;
    const int half = blockIdx.y;
    const int tid = threadIdx.x;
#pragma unroll
    for (int h = 0; h < 2; ++h) {
        int m = tid + h * 1024;
        const float* sp = Spart + ((size_t)ns * LL + m) * 16;
        double a = 0.0;
#pragma unroll
        for (int t = 0; t < 16; ++t) a += (double)sp[t];
        s[m] = a;
    }
    __syncthreads();
    const int i = half * 1024 + tid;
    const double si = s[i];
    int cnt = 0;
    for (int j = 0; j < LL; ++j) cnt += (s[j] < si) ? 1 : 0;
    maskbuf[ns * LL + i] = (cnt < 1024) ? 1 : 0;
}

// ---------------------------------------------------------------------------
// Kernel 6: blend, all fp32.
// ---------------------------------------------------------------------------
__global__ __launch_bounds__(256) void blend_kernel(
    const float* __restrict__ xt, const float* __restrict__ xf,
    const unsigned char* __restrict__ maskbuf, float* __restrict__ out)
{
    const int idx4 = blockIdx.x * 256 + threadIdx.x;
    const size_t q = (size_t)idx4 * 4;
    const int row = (int)(q >> 7);
    const float4 a = *(const float4*)(xt + q);
    const float4 b = *(const float4*)(xf + q);
    const int mt = maskbuf[row] & 1;
    const int mf = maskbuf[16384 + row] & 1;
    const bool ct = mt && !mf;
    const bool cf = mf && !mt;
    float4 av;
    av.x = 0.5f * (a.x + b.x);  av.y = 0.5f * (a.y + b.y);
    av.z = 0.5f * (a.z + b.z);  av.w = 0.5f * (a.w + b.w);
    float4 o0 = ct ? av : a;
    float4 o1 = cf ? av : b;
    *(float4*)(out + q)                   = o0;
    *(float4*)(out + (size_t)2097152 + q) = o1;
}

// ---------------------------------------------------------------------------
extern "C" void kernel_launch(void* const* d_in, const int* in_sizes, int n_in,
                              void* d_out, int out_size, void* d_ws, size_t ws_size,
                              hipStream_t stream)
{
    const float* xt = (const float*)d_in[0];
    const float* xf = (const float*)d_in[1];
    const float* W  = (const float*)d_in[2];
    const float* b  = (const float*)d_in[3];
    float* out = (float*)d_out;

    // d_out (16.8 MB) holds P split: Ph bf16 [0,8.39MB), Pl bf16 [8.39,16.8MB).
    // Both dead before blend overwrites d_out.
    unsigned short* Ph = (unsigned short*)d_out;
    unsigned short* Pl = Ph + (size_t)NS * SLAB;

    float* Zpart = (float*)d_ws;                       // 16*16*2048 = 524288 f
    float* iZfin = Zpart + 16 * 16 * LL;               // 32768 f
    float* Spart = iZfin + NS * LL;                    // 524288 f
    unsigned char* maskbuf = (unsigned char*)(Spart + (size_t)16 * LL * 16);
    // total ws ~4.4 MB

    proj_kernel<<<dim3(32, NS), 256, 0, stream>>>(xt, xf, W, b, Ph, Pl);
    stats_kernel<<<dim3(NPAIR, NS), 256, 0, stream>>>(Ph, Pl, Zpart);
    reduce_stats_kernel<<<128, 256, 0, stream>>>(Zpart, iZfin);
    colsum_kernel<<<dim3(NPAIR, NS), 256, 0, stream>>>(Ph, Pl, iZfin, Spart);
    mask_kernel<<<dim3(NS, 2), 1024, 0, stream>>>(Spart, maskbuf);
    blend_kernel<<<2048, 256, 0, stream>>>(xt, xf, maskbuf, out);
}

// Round 3
// 234.027 us; speedup vs baseline: 1.2578x; 1.2578x over previous
//
#include <hip/hip_runtime.h>
#include <math.h>

#define LL 2048
#define DD 128
#define NS 16                          // 2 sources * 8 batches
#define SLAB (LL * DD)                 // 262144 elements per (src,n)
#define SCALE 0.08838834764831845f     // 1/sqrt(128)
#define NT 16                          // 128-row tiles per slab
#define NPAIR 136                      // NT*(NT+1)/2 upper-triangle pairs

typedef __attribute__((ext_vector_type(8))) short short8v;   // 8 bf16 (4 VGPR)
typedef __attribute__((ext_vector_type(4))) float float4v;   // MFMA C/D

__device__ __forceinline__ unsigned int f2bf(float f) {   // RNE, low 16 bits
    unsigned int u = __float_as_uint(f);
    u += 0x7fffu + ((u >> 16) & 1u);
    return u >> 16;
}
__device__ __forceinline__ void pair_decode(int p, int& ib, int& jb) {
    int i = 0;
    while (p >= NT - i) { p -= NT - i; ++i; }
    ib = i; jb = i + p;
}

// ns-first XCD remap: HW round-robins linear workgroup id over 8 XCDs
// (x-major). Give XCD k the two slabs ns=k and ns=k+8 (1 MB each, Ph+Pl)
// so each XCD's L2 (4 MB) holds its entire working set. Bijective for any
// HW mapping (pure permutation of work).
__device__ __forceinline__ void work_decode(int bx, int by, int& pair, int& ns) {
    const int lin = by * NPAIR + bx;
    const int xcd = lin & 7;
    const int wi  = lin >> 3;          // 0..271
    const int h   = (wi >= NPAIR) ? 1 : 0;
    ns   = xcd + 8 * h;
    pair = wi - NPAIR * h;
}

// async global->LDS, 16B per lane; LDS dest = wave-uniform base + lane*16
__device__ __forceinline__ void gl_lds16(const void* g, void* l) {
    __builtin_amdgcn_global_load_lds(
        (const __attribute__((address_space(1))) void*)g,
        (__attribute__((address_space(3))) void*)l, 16, 0, 0);
}

// Stage one 128x32 bf16 chunk of tile gT (already offset to kc*32 cols) into
// panel lbuf of 512 x 16B slots. Slot s = row*4 + c' holds the row's 16B
// chunk oc = c' ^ ((row>>1)&3)  (XOR involution: same perm applied on read).
// LDS dest is linear (gl_lds requirement, rule 21: linear dest + swizzled
// SOURCE + swizzled READ). Write side: wave covers 1024 contiguous LDS bytes
// (dense). Read side (row=base+l16, chunk=quad): 16 rows x full 64B each,
// dense 1024B per ds_read_b128 -> conflict-free.
__device__ __forceinline__ void stage_panel(
    const unsigned short* __restrict__ gT, unsigned short* lbuf, int tid)
{
#pragma unroll
    for (int it = 0; it < 2; ++it) {
        const int s   = tid + it * 256;
        const int sb  = (tid & ~63) + it * 256;   // wave-uniform base slot
        const int row = s >> 2;
        const int oc  = (s & 3) ^ ((row >> 1) & 3);
        gl_lds16(gT + (size_t)row * DD + oc * 8, lbuf + (size_t)sb * 8);
    }
}

// ---------------------------------------------------------------------------
// Kernel 1: P = x @ W^T + b (fp32), split to P_hi/P_lo bf16 in d_out.
// Block: 64 l-rows x 128 d. Grid: (32 l-tiles, 16 ns) = 512 blocks.
// ---------------------------------------------------------------------------
__global__ __launch_bounds__(256, 4) void proj_kernel(
    const float* __restrict__ xt, const float* __restrict__ xf,
    const float* __restrict__ W,  const float* __restrict__ bias,
    unsigned short* __restrict__ Ph, unsigned short* __restrict__ Pl)
{
    __shared__ float Alds[64 * 36];
    __shared__ float Blds[128 * 36];
    __shared__ float bs[128];
    const int ns = blockIdx.y;
    const int l0 = blockIdx.x * 64;
    const int src = ns >> 3, n = ns & 7;
    const float* x = (src ? xf : xt) + (size_t)n * LL * DD;
    const int tid = threadIdx.x;
    const int ty = tid >> 4, tx = tid & 15;

    if (tid < 128) bs[tid] = bias[tid];
    __syncthreads();

    float acc[4][8];
#pragma unroll
    for (int i = 0; i < 4; ++i)
#pragma unroll
        for (int j = 0; j < 8; ++j) acc[i][j] = bs[tx + 16 * j];

    for (int kc = 0; kc < 4; ++kc) {
        __syncthreads();
#pragma unroll
        for (int t = 0; t < 2; ++t) {            // x: 64 x 32 = 512 float4
            int idx = tid + t * 256;
            int r = idx >> 3, k4 = (idx & 7) << 2;
            *(float4*)&Alds[r * 36 + k4] =
                *(const float4*)&x[(size_t)(l0 + r) * DD + kc * 32 + k4];
        }
#pragma unroll
        for (int t = 0; t < 4; ++t) {            // W: 128 x 32 = 1024 float4
            int idx = tid + t * 256;
            int r = idx >> 3, k4 = (idx & 7) << 2;
            *(float4*)&Blds[r * 36 + k4] =
                *(const float4*)&W[(size_t)r * DD + kc * 32 + k4];
        }
        __syncthreads();
#pragma unroll
        for (int k4 = 0; k4 < 32; k4 += 4) {
            float4 a4[4], b4[8];
#pragma unroll
            for (int i = 0; i < 4; ++i) a4[i] = *(const float4*)&Alds[(ty + 16 * i) * 36 + k4];
#pragma unroll
            for (int j = 0; j < 8; ++j) b4[j] = *(const float4*)&Blds[(tx + 16 * j) * 36 + k4];
#pragma unroll
            for (int i = 0; i < 4; ++i)
#pragma unroll
                for (int j = 0; j < 8; ++j) {
                    acc[i][j] = fmaf(a4[i].x, b4[j].x, acc[i][j]);
                    acc[i][j] = fmaf(a4[i].y, b4[j].y, acc[i][j]);
                    acc[i][j] = fmaf(a4[i].z, b4[j].z, acc[i][j]);
                    acc[i][j] = fmaf(a4[i].w, b4[j].w, acc[i][j]);
                }
        }
    }
#pragma unroll
    for (int i = 0; i < 4; ++i) {
        const size_t rowo = (size_t)ns * SLAB + (size_t)(l0 + ty + 16 * i) * DD;
#pragma unroll
        for (int j = 0; j < 8; ++j) {
            float p = acc[i][j];
            unsigned int hb = f2bf(p);
            float hf = __uint_as_float(hb << 16);
            unsigned int lb = f2bf(p - hf);
            Ph[rowo + tx + 16 * j] = (unsigned short)hb;
            Pl[rowo + tx + 16 * j] = (unsigned short)lb;
        }
    }
}

// ---------------------------------------------------------------------------
// MFMA bf16x3 GEMM core v4 (hi*hi + hi*lo + lo*hi).
// 4 waves in 2x2 grid; each wave owns a 64x64 quadrant of S(ib,jb).
// T3-minimum 2-phase pipeline: prefetch kc+1 into the other buffer BEFORE
// computing kc; ONE barrier (vmcnt drain) per kc. A and B both in LDS
// (R1 lesson), double-buffered (R2 lesson: single-buffer serializes).
// Diag pairs (ib==jb) alias B panels to A panels (half the staging).
// acc frag (16x16x32): out row = quad*4 + reg, out col = l16.
// ---------------------------------------------------------------------------
__device__ __forceinline__ void mfma_core(
    const unsigned short* __restrict__ Ph, const unsigned short* __restrict__ Pl,
    int ns, int ib, int jb, int tid,
    unsigned short (*pan)[4096],          // [buf*4 + {Ah,Al,Bh,Bl}]
    float4v (&acc)[4][4])
{
    const int lane = tid & 63;
    const int quad = lane >> 4, l16 = lane & 15;
    const int wave = tid >> 6;
    const int wr = wave >> 1, wc = wave & 1;
    const bool dg = (ib == jb);

    const unsigned short* sAh = Ph + (size_t)ns * SLAB + (size_t)ib * 128 * DD;
    const unsigned short* sAl = Pl + (size_t)ns * SLAB + (size_t)ib * 128 * DD;
    const unsigned short* sBh = Ph + (size_t)ns * SLAB + (size_t)jb * 128 * DD;
    const unsigned short* sBl = Pl + (size_t)ns * SLAB + (size_t)jb * 128 * DD;

#pragma unroll
    for (int i = 0; i < 4; ++i)
#pragma unroll
        for (int j = 0; j < 4; ++j)
#pragma unroll
            for (int r = 0; r < 4; ++r) acc[i][j][r] = 0.f;

    // prologue: stage kc=0 into buffer 0
    stage_panel(sAh, pan[0], tid);
    stage_panel(sAl, pan[1], tid);
    if (!dg) {
        stage_panel(sBh, pan[2], tid);
        stage_panel(sBl, pan[3], tid);
    }
    __syncthreads();                       // compiler drains vmcnt(0) here

#pragma unroll
    for (int kc = 0; kc < 4; ++kc) {
        const int cur = (kc & 1) * 4;
        if (kc < 3) {                      // prefetch next chunk, other buffer
            const int nxt = ((kc + 1) & 1) * 4;
            stage_panel(sAh + (kc + 1) * 32, pan[nxt + 0], tid);
            stage_panel(sAl + (kc + 1) * 32, pan[nxt + 1], tid);
            if (!dg) {
                stage_panel(sBh + (kc + 1) * 32, pan[nxt + 2], tid);
                stage_panel(sBl + (kc + 1) * 32, pan[nxt + 3], tid);
            }
        }
        const unsigned short* Ah = pan[cur + 0];
        const unsigned short* Al = pan[cur + 1];
        const unsigned short* Bh = dg ? pan[cur + 0] : pan[cur + 2];
        const unsigned short* Bl = dg ? pan[cur + 1] : pan[cur + 3];

        short8v ah[4], al[4], bh[4], bl[4];
#pragma unroll
        for (int rt = 0; rt < 4; ++rt) {
            const int r = wr * 64 + rt * 16 + l16;
            const int off = r * 32 + ((quad ^ ((r >> 1) & 3)) << 3);
            ah[rt] = *(const short8v*)&Ah[off];
            al[rt] = *(const short8v*)&Al[off];
        }
#pragma unroll
        for (int ct = 0; ct < 4; ++ct) {
            const int r = wc * 64 + ct * 16 + l16;
            const int off = r * 32 + ((quad ^ ((r >> 1) & 3)) << 3);
            bh[ct] = *(const short8v*)&Bh[off];
            bl[ct] = *(const short8v*)&Bl[off];
        }
#pragma unroll
        for (int rt = 0; rt < 4; ++rt)
#pragma unroll
            for (int ct = 0; ct < 4; ++ct) {
                acc[rt][ct] = __builtin_amdgcn_mfma_f32_16x16x32_bf16(ah[rt], bh[ct], acc[rt][ct], 0, 0, 0);
                acc[rt][ct] = __builtin_amdgcn_mfma_f32_16x16x32_bf16(ah[rt], bl[ct], acc[rt][ct], 0, 0, 0);
                acc[rt][ct] = __builtin_amdgcn_mfma_f32_16x16x32_bf16(al[rt], bh[ct], acc[rt][ct], 0, 0, 0);
            }
        if (kc < 3) __syncthreads();       // drains prefetch vmcnt; frees cur buf
    }
}

// ---------------------------------------------------------------------------
// Kernel 2: per tile-pair UNSHIFTED softmax denominators: Zpart row sums of
// exp(s) for rows of BOTH blocks. Zpart: [(ns*16 + othertile)*2048 + row]
// ---------------------------------------------------------------------------
__global__ __launch_bounds__(256, 2) void stats_kernel(
    const unsigned short* __restrict__ Ph, const unsigned short* __restrict__ Pl,
    float* __restrict__ Zpart)
{
    __shared__ unsigned short pan[8][4096];                 // 64 KB panels
    __shared__ float Zr[128][2], Zc[128][2];                // 2 KB
    int pair, ns;  work_decode(blockIdx.x, blockIdx.y, pair, ns);
    int ib, jb;    pair_decode(pair, ib, jb);
    const int tid = threadIdx.x;
    const int lane = tid & 63, quad = lane >> 4, l16 = lane & 15, wave = tid >> 6;
    const int wr = wave >> 1, wc = wave & 1;

    float4v acc[4][4];
    mfma_core(Ph, Pl, ns, ib, jb, tid, pan, acc);

    float cs[4] = {0.f, 0.f, 0.f, 0.f};
#pragma unroll
    for (int rt = 0; rt < 4; ++rt)
#pragma unroll
        for (int rg = 0; rg < 4; ++rg) {
            float e[4];
            float s = 0.f;
#pragma unroll
            for (int ct = 0; ct < 4; ++ct) {
                e[ct] = __expf(acc[rt][ct][rg] * SCALE);
                s += e[ct]; cs[ct] += e[ct];
            }
            s += __shfl_xor(s, 1);
            s += __shfl_xor(s, 2);
            s += __shfl_xor(s, 4);
            s += __shfl_xor(s, 8);
            if (l16 == 0) Zr[wr * 64 + rt * 16 + quad * 4 + rg][wc] = s;
        }

    // transpose partials: sums over this wave's 64 rows for its 64 cols
#pragma unroll
    for (int ct = 0; ct < 4; ++ct) {
        float s = cs[ct];
        s += __shfl_xor(s, 16);
        s += __shfl_xor(s, 32);
        if (quad == 0) Zc[wc * 64 + ct * 16 + l16][wr] = s;
    }
    __syncthreads();
    if (tid < 128) {
        Zpart[(ns * 16 + jb) * LL + ib * 128 + tid] = Zr[tid][0] + Zr[tid][1];
        if (ib != jb)
            Zpart[(ns * 16 + ib) * LL + jb * 128 + tid] = Zc[tid][0] + Zc[tid][1];
    }
}

// ---------------------------------------------------------------------------
// Kernel 3: iZ[row] = 1 / sum of 16 per-tile partials
// ---------------------------------------------------------------------------
__global__ __launch_bounds__(256) void reduce_stats_kernel(
    const float* __restrict__ Zpart, float* __restrict__ iZfin)
{
    const int idx = blockIdx.x * 256 + threadIdx.x;   // ns*2048 + l
    const int ns = idx >> 11, l = idx & 2047;
    float Z = 0.f;
#pragma unroll
    for (int t = 0; t < 16; ++t) Z += Zpart[(ns * 16 + t) * LL + l];
    iZfin[idx] = 1.0f / Z;
}

// ---------------------------------------------------------------------------
// Kernel 4: recompute s (identical MFMA sequence), per-tile column partial
// sums of exp(s)*iZ_row for cols of BOTH blocks. Spart: [(ns*2048+m)*16+tile]
// ---------------------------------------------------------------------------
__global__ __launch_bounds__(256, 2) void colsum_kernel(
    const unsigned short* __restrict__ Ph, const unsigned short* __restrict__ Pl,
    const float* __restrict__ iZfin, float* __restrict__ Spart)
{
    __shared__ unsigned short pan[8][4096];                 // 64 KB panels
    __shared__ float Sr[128][2], Sc[128][2];                // 2 KB
    int pair, ns;  work_decode(blockIdx.x, blockIdx.y, pair, ns);
    int ib, jb;    pair_decode(pair, ib, jb);
    const int tid = threadIdx.x;
    const int lane = tid & 63, quad = lane >> 4, l16 = lane & 15, wave = tid >> 6;
    const int wr = wave >> 1, wc = wave & 1;

    float4v acc[4][4];
    mfma_core(Ph, Pl, ns, ib, jb, tid, pan, acc);

    float wrow[4][4];
#pragma unroll
    for (int rt = 0; rt < 4; ++rt)
#pragma unroll
        for (int rg = 0; rg < 4; ++rg)
            wrow[rt][rg] = iZfin[ns * LL + ib * 128 + wr * 64 + rt * 16 + quad * 4 + rg];
    float wcol[4];
#pragma unroll
    for (int ct = 0; ct < 4; ++ct)
        wcol[ct] = iZfin[ns * LL + jb * 128 + wc * 64 + ct * 16 + l16];

    float dsum[4] = {0.f, 0.f, 0.f, 0.f};
#pragma unroll
    for (int rt = 0; rt < 4; ++rt)
#pragma unroll
        for (int rg = 0; rg < 4; ++rg) {
            const int rl = wr * 64 + rt * 16 + quad * 4 + rg;
            float ts = 0.f;
#pragma unroll
            for (int ct = 0; ct < 4; ++ct) {
                float e = __expf(acc[rt][ct][rg] * SCALE);
                bool diag = (ib == jb) && (rl == wc * 64 + ct * 16 + l16);
                dsum[ct] += diag ? 0.f : e * wrow[rt][rg];
                ts += e * wcol[ct];
            }
            if (ib != jb) {
                ts += __shfl_xor(ts, 1);
                ts += __shfl_xor(ts, 2);
                ts += __shfl_xor(ts, 4);
                ts += __shfl_xor(ts, 8);
                if (l16 == 0) Sr[rl][wc] = ts;
            }
        }

#pragma unroll
    for (int ct = 0; ct < 4; ++ct) {
        float s = dsum[ct];
        s += __shfl_xor(s, 16);
        s += __shfl_xor(s, 32);
        if (quad == 0) Sc[wc * 64 + ct * 16 + l16][wr] = s;
    }
    __syncthreads();
    if (tid < 128) {
        Spart[((size_t)ns * LL + jb * 128 + tid) * 16 + ib] = Sc[tid][0] + Sc[tid][1];
        if (ib != jb)
            Spart[((size_t)ns * LL + ib * 128 + tid) * 16 + jb] = Sr[tid][0] + Sr[tid][1];
    }
}

// ---------------------------------------------------------------------------
// Kernel 5: score = fp64 sum of 16 tile partials; exact bottom-k mask via
// rank counting: mask[i] = #{j: score_j < score_i} < 1024
// ---------------------------------------------------------------------------
__global__ __launch_bounds__(1024) void mask_kernel(
    const float* __restrict__ Spart, unsigned char* __restrict__ maskbuf)
{
    __shared__ double s[LL];
    const int ns = blockIdx.x;
    const int half = blockIdx.y;
    const int tid = threadIdx.x;
#pragma unroll
    for (int h = 0; h < 2; ++h) {
        int m = tid + h * 1024;
        const float* sp = Spart + ((size_t)ns * LL + m) * 16;
        double a = 0.0;
#pragma unroll
        for (int t = 0; t < 16; ++t) a += (double)sp[t];
        s[m] = a;
    }
    __syncthreads();
    const int i = half * 1024 + tid;
    const double si = s[i];
    int cnt = 0;
    for (int j = 0; j < LL; ++j) cnt += (s[j] < si) ? 1 : 0;
    maskbuf[ns * LL + i] = (cnt < 1024) ? 1 : 0;
}

// ---------------------------------------------------------------------------
// Kernel 6: blend, all fp32.
// ---------------------------------------------------------------------------
__global__ __launch_bounds__(256) void blend_kernel(
    const float* __restrict__ xt, const float* __restrict__ xf,
    const unsigned char* __restrict__ maskbuf, float* __restrict__ out)
{
    const int idx4 = blockIdx.x * 256 + threadIdx.x;
    const size_t q = (size_t)idx4 * 4;
    const int row = (int)(q >> 7);
    const float4 a = *(const float4*)(xt + q);
    const float4 b = *(const float4*)(xf + q);
    const int mt = maskbuf[row] & 1;
    const int mf = maskbuf[16384 + row] & 1;
    const bool ct = mt && !mf;
    const bool cf = mf && !mt;
    float4 av;
    av.x = 0.5f * (a.x + b.x);  av.y = 0.5f * (a.y + b.y);
    av.z = 0.5f * (a.z + b.z);  av.w = 0.5f * (a.w + b.w);
    float4 o0 = ct ? av : a;
    float4 o1 = cf ? av : b;
    *(float4*)(out + q)                   = o0;
    *(float4*)(out + (size_t)2097152 + q) = o1;
}

// ---------------------------------------------------------------------------
extern "C" void kernel_launch(void* const* d_in, const int* in_sizes, int n_in,
                              void* d_out, int out_size, void* d_ws, size_t ws_size,
                              hipStream_t stream)
{
    const float* xt = (const float*)d_in[0];
    const float* xf = (const float*)d_in[1];
    const float* W  = (const float*)d_in[2];
    const float* b  = (const float*)d_in[3];
    float* out = (float*)d_out;

    // d_out (16.8 MB) holds P split: Ph bf16 [0,8.39MB), Pl bf16 [8.39,16.8MB).
    // Both dead before blend overwrites d_out.
    unsigned short* Ph = (unsigned short*)d_out;
    unsigned short* Pl = Ph + (size_t)NS * SLAB;

    float* Zpart = (float*)d_ws;                       // 16*16*2048 = 524288 f
    float* iZfin = Zpart + 16 * 16 * LL;               // 32768 f
    float* Spart = iZfin + NS * LL;                    // 524288 f
    unsigned char* maskbuf = (unsigned char*)(Spart + (size_t)16 * LL * 16);
    // total ws ~4.4 MB

    proj_kernel<<<dim3(32, NS), 256, 0, stream>>>(xt, xf, W, b, Ph, Pl);
    stats_kernel<<<dim3(NPAIR, NS), 256, 0, stream>>>(Ph, Pl, Zpart);
    reduce_stats_kernel<<<128, 256, 0, stream>>>(Zpart, iZfin);
    colsum_kernel<<<dim3(NPAIR, NS), 256, 0, stream>>>(Ph, Pl, iZfin, Spart);
    mask_kernel<<<dim3(NS, 2), 1024, 0, stream>>>(Spart, maskbuf);
    blend_kernel<<<2048, 256, 0, stream>>>(xt, xf, maskbuf, out);
}

// Round 4
// 230.346 us; speedup vs baseline: 1.2779x; 1.0160x over previous
//
#include <hip/hip_runtime.h>
#include <math.h>

#define LL 2048
#define DD 128
#define NS 16                          // 2 sources * 8 batches
#define SLAB (LL * DD)                 // 262144 elements per (src,n)
#define SCALE 0.08838834764831845f     // 1/sqrt(128)
#define NT 16                          // 128-row tiles per slab
#define NPAIR 136                      // NT*(NT+1)/2 upper-triangle pairs

typedef __attribute__((ext_vector_type(8))) short short8v;   // 8 bf16 (4 VGPR)
typedef __attribute__((ext_vector_type(4))) float float4v;   // MFMA C/D

__device__ __forceinline__ unsigned int f2bf(float f) {   // RNE, low 16 bits
    unsigned int u = __float_as_uint(f);
    u += 0x7fffu + ((u >> 16) & 1u);
    return u >> 16;
}
__device__ __forceinline__ void pair_decode(int p, int& ib, int& jb) {
    int i = 0;
    while (p >= NT - i) { p -= NT - i; ++i; }
    ib = i; jb = i + p;
}

// ns-first XCD remap (R3 win: FETCH 90->8.3 MB). XCD k owns slabs ns=k,k+8
// (1 MB each Ph+Pl) -> entire working set L2-resident per XCD.
__device__ __forceinline__ void work_decode(int bx, int by, int& pair, int& ns) {
    const int lin = by * NPAIR + bx;
    const int xcd = lin & 7;
    const int wi  = lin >> 3;          // 0..271
    const int h   = (wi >= NPAIR) ? 1 : 0;
    ns   = xcd + 8 * h;
    pair = wi - NPAIR * h;
}

// async global->LDS, 16B per lane; LDS dest = wave-uniform base + lane*16
__device__ __forceinline__ void gl_lds16(const void* g, void* l) {
    __builtin_amdgcn_global_load_lds(
        (const __attribute__((address_space(1))) void*)g,
        (__attribute__((address_space(3))) void*)l, 16, 0, 0);
}

// Stage one 128x32 bf16 chunk into a 512x16B-slot panel. Slot s = row*4+c'
// holds row's chunk oc = c' ^ ((row>>1)&3) (XOR involution, applied again on
// read). Linear LDS dest (gl_lds requirement), swizzled SOURCE + swizzled
// READ -> conflict-free ds_read_b128 (verified R3: SQ_LDS_BANK_CONFLICT=0).
__device__ __forceinline__ void stage_panel(
    const unsigned short* __restrict__ gT, unsigned short* lbuf, int tid)
{
#pragma unroll
    for (int it = 0; it < 2; ++it) {
        const int s   = tid + it * 256;
        const int sb  = (tid & ~63) + it * 256;   // wave-uniform base slot
        const int row = s >> 2;
        const int oc  = (s & 3) ^ ((row >> 1) & 3);
        gl_lds16(gT + (size_t)row * DD + oc * 8, lbuf + (size_t)sb * 8);
    }
}

// ---------------------------------------------------------------------------
// Kernel 1: P = x @ W^T + b (fp32), split to P_hi/P_lo bf16 in d_out.
// Block: 64 l-rows x 128 d. Grid: (32 l-tiles, 16 ns) = 512 blocks.
// ---------------------------------------------------------------------------
__global__ __launch_bounds__(256, 4) void proj_kernel(
    const float* __restrict__ xt, const float* __restrict__ xf,
    const float* __restrict__ W,  const float* __restrict__ bias,
    unsigned short* __restrict__ Ph, unsigned short* __restrict__ Pl)
{
    __shared__ float Alds[64 * 36];
    __shared__ float Blds[128 * 36];
    __shared__ float bs[128];
    const int ns = blockIdx.y;
    const int l0 = blockIdx.x * 64;
    const int src = ns >> 3, n = ns & 7;
    const float* x = (src ? xf : xt) + (size_t)n * LL * DD;
    const int tid = threadIdx.x;
    const int ty = tid >> 4, tx = tid & 15;

    if (tid < 128) bs[tid] = bias[tid];
    __syncthreads();

    float acc[4][8];
#pragma unroll
    for (int i = 0; i < 4; ++i)
#pragma unroll
        for (int j = 0; j < 8; ++j) acc[i][j] = bs[tx + 16 * j];

    for (int kc = 0; kc < 4; ++kc) {
        __syncthreads();
#pragma unroll
        for (int t = 0; t < 2; ++t) {            // x: 64 x 32 = 512 float4
            int idx = tid + t * 256;
            int r = idx >> 3, k4 = (idx & 7) << 2;
            *(float4*)&Alds[r * 36 + k4] =
                *(const float4*)&x[(size_t)(l0 + r) * DD + kc * 32 + k4];
        }
#pragma unroll
        for (int t = 0; t < 4; ++t) {            // W: 128 x 32 = 1024 float4
            int idx = tid + t * 256;
            int r = idx >> 3, k4 = (idx & 7) << 2;
            *(float4*)&Blds[r * 36 + k4] =
                *(const float4*)&W[(size_t)r * DD + kc * 32 + k4];
        }
        __syncthreads();
#pragma unroll
        for (int k4 = 0; k4 < 32; k4 += 4) {
            float4 a4[4], b4[8];
#pragma unroll
            for (int i = 0; i < 4; ++i) a4[i] = *(const float4*)&Alds[(ty + 16 * i) * 36 + k4];
#pragma unroll
            for (int j = 0; j < 8; ++j) b4[j] = *(const float4*)&Blds[(tx + 16 * j) * 36 + k4];
#pragma unroll
            for (int i = 0; i < 4; ++i)
#pragma unroll
                for (int j = 0; j < 8; ++j) {
                    acc[i][j] = fmaf(a4[i].x, b4[j].x, acc[i][j]);
                    acc[i][j] = fmaf(a4[i].y, b4[j].y, acc[i][j]);
                    acc[i][j] = fmaf(a4[i].z, b4[j].z, acc[i][j]);
                    acc[i][j] = fmaf(a4[i].w, b4[j].w, acc[i][j]);
                }
        }
    }
#pragma unroll
    for (int i = 0; i < 4; ++i) {
        const size_t rowo = (size_t)ns * SLAB + (size_t)(l0 + ty + 16 * i) * DD;
#pragma unroll
        for (int j = 0; j < 8; ++j) {
            float p = acc[i][j];
            unsigned int hb = f2bf(p);
            float hf = __uint_as_float(hb << 16);
            unsigned int lb = f2bf(p - hf);
            Ph[rowo + tx + 16 * j] = (unsigned short)hb;
            Pl[rowo + tx + 16 * j] = (unsigned short)lb;
        }
    }
}

// ---------------------------------------------------------------------------
// MFMA bf16x3 GEMM core v5 (hi*hi + hi*lo + lo*hi).
// 4 waves in 2x2 grid; wave owns a 64x64 quadrant of S(ib,jb).
// LDS: only {Ah,Bh,Bl} panels, double-buffered (48 KB) -> 3 blocks/CU.
// A-lo frags live in REGISTERS, direct-global with distance-1 prefetch
// (R1 failed at distance-0; R3's XCD remap makes these L2 hits).
// T3-minimum pipeline: prefetch kc+1 before compute kc; 1 barrier per kc.
// Numerics identical to R0-R3: same products, same accumulation order.
// acc frag (16x16x32): out row = quad*4 + reg, out col = l16.
// ---------------------------------------------------------------------------
__device__ __forceinline__ void mfma_core(
    const unsigned short* __restrict__ Ph, const unsigned short* __restrict__ Pl,
    int ns, int ib, int jb, int tid,
    unsigned short (*pan)[4096],          // [buf*3 + {Ah,Bh,Bl}]
    float4v (&acc)[4][4])
{
    const int lane = tid & 63;
    const int quad = lane >> 4, l16 = lane & 15;
    const int wave = tid >> 6;
    const int wr = wave >> 1, wc = wave & 1;
    const bool dg = (ib == jb);

    const unsigned short* sAh = Ph + (size_t)ns * SLAB + (size_t)ib * 128 * DD;
    const unsigned short* sAl = Pl + (size_t)ns * SLAB + (size_t)ib * 128 * DD;
    const unsigned short* sBh = Ph + (size_t)ns * SLAB + (size_t)jb * 128 * DD;
    const unsigned short* sBl = Pl + (size_t)ns * SLAB + (size_t)jb * 128 * DD;

    // per-wave A-lo row pointers: row = wr*64 + rt*16 + l16, col base quad*8
    const unsigned short* alp[4];
#pragma unroll
    for (int rt = 0; rt < 4; ++rt)
        alp[rt] = sAl + (size_t)(wr * 64 + rt * 16 + l16) * DD + quad * 8;

#pragma unroll
    for (int i = 0; i < 4; ++i)
#pragma unroll
        for (int j = 0; j < 4; ++j)
#pragma unroll
            for (int r = 0; r < 4; ++r) acc[i][j][r] = 0.f;

    // prologue: stage kc=0 panels + load kc=0 A-lo regs
    stage_panel(sAh, pan[0], tid);
    if (!dg) stage_panel(sBh, pan[1], tid);
    stage_panel(sBl, pan[2], tid);
    short8v alr[2][4];                     // 2-deep reg buffer (static idx only)
#pragma unroll
    for (int rt = 0; rt < 4; ++rt) alr[0][rt] = *(const short8v*)&alp[rt][0];
    __syncthreads();                       // drains vmcnt(0)

#pragma unroll
    for (int kc = 0; kc < 4; ++kc) {
        const int cur = (kc & 1) * 3;      // compile-time under full unroll
        if (kc < 3) {                      // prefetch kc+1: panels + A-lo regs
            const int nxt = ((kc + 1) & 1) * 3;
            stage_panel(sAh + (kc + 1) * 32, pan[nxt + 0], tid);
            if (!dg) stage_panel(sBh + (kc + 1) * 32, pan[nxt + 1], tid);
            stage_panel(sBl + (kc + 1) * 32, pan[nxt + 2], tid);
#pragma unroll
            for (int rt = 0; rt < 4; ++rt)
                alr[(kc + 1) & 1][rt] = *(const short8v*)&alp[rt][(kc + 1) * 32];
        }
        const unsigned short* AhP = pan[cur + 0];
        const unsigned short* BhP = dg ? pan[cur + 0] : pan[cur + 1];
        const unsigned short* BlP = pan[cur + 2];

        short8v ah[4], bh[4], bl[4];
#pragma unroll
        for (int rt = 0; rt < 4; ++rt) {
            const int r = wr * 64 + rt * 16 + l16;
            const int off = r * 32 + ((quad ^ ((r >> 1) & 3)) << 3);
            ah[rt] = *(const short8v*)&AhP[off];
        }
#pragma unroll
        for (int ct = 0; ct < 4; ++ct) {
            const int r = wc * 64 + ct * 16 + l16;
            const int off = r * 32 + ((quad ^ ((r >> 1) & 3)) << 3);
            bh[ct] = *(const short8v*)&BhP[off];
            bl[ct] = *(const short8v*)&BlP[off];
        }
        __builtin_amdgcn_s_setprio(1);
#pragma unroll
        for (int rt = 0; rt < 4; ++rt)
#pragma unroll
            for (int ct = 0; ct < 4; ++ct) {
                acc[rt][ct] = __builtin_amdgcn_mfma_f32_16x16x32_bf16(ah[rt], bh[ct], acc[rt][ct], 0, 0, 0);
                acc[rt][ct] = __builtin_amdgcn_mfma_f32_16x16x32_bf16(ah[rt], bl[ct], acc[rt][ct], 0, 0, 0);
                acc[rt][ct] = __builtin_amdgcn_mfma_f32_16x16x32_bf16(alr[kc & 1][rt], bh[ct], acc[rt][ct], 0, 0, 0);
            }
        __builtin_amdgcn_s_setprio(0);
        if (kc < 3) __syncthreads();       // drains prefetch vmcnt; frees cur buf
    }
}

// ---------------------------------------------------------------------------
// Kernel 2: per tile-pair UNSHIFTED softmax denominators: Zpart row sums of
// exp(s) for rows of BOTH blocks. Zpart: [(ns*16 + othertile)*2048 + row]
// ---------------------------------------------------------------------------
__global__ __launch_bounds__(256, 3) void stats_kernel(
    const unsigned short* __restrict__ Ph, const unsigned short* __restrict__ Pl,
    float* __restrict__ Zpart)
{
    __shared__ unsigned short pan[6][4096];                 // 48 KB panels
    __shared__ float Zr[128][2], Zc[128][2];                // 2 KB
    int pair, ns;  work_decode(blockIdx.x, blockIdx.y, pair, ns);
    int ib, jb;    pair_decode(pair, ib, jb);
    const int tid = threadIdx.x;
    const int lane = tid & 63, quad = lane >> 4, l16 = lane & 15, wave = tid >> 6;
    const int wr = wave >> 1, wc = wave & 1;

    float4v acc[4][4];
    mfma_core(Ph, Pl, ns, ib, jb, tid, pan, acc);

    float cs[4] = {0.f, 0.f, 0.f, 0.f};
#pragma unroll
    for (int rt = 0; rt < 4; ++rt)
#pragma unroll
        for (int rg = 0; rg < 4; ++rg) {
            float e[4];
            float s = 0.f;
#pragma unroll
            for (int ct = 0; ct < 4; ++ct) {
                e[ct] = __expf(acc[rt][ct][rg] * SCALE);
                s += e[ct]; cs[ct] += e[ct];
            }
            s += __shfl_xor(s, 1);
            s += __shfl_xor(s, 2);
            s += __shfl_xor(s, 4);
            s += __shfl_xor(s, 8);
            if (l16 == 0) Zr[wr * 64 + rt * 16 + quad * 4 + rg][wc] = s;
        }

    // transpose partials: sums over this wave's 64 rows for its 64 cols
#pragma unroll
    for (int ct = 0; ct < 4; ++ct) {
        float s = cs[ct];
        s += __shfl_xor(s, 16);
        s += __shfl_xor(s, 32);
        if (quad == 0) Zc[wc * 64 + ct * 16 + l16][wr] = s;
    }
    __syncthreads();
    if (tid < 128) {
        Zpart[(ns * 16 + jb) * LL + ib * 128 + tid] = Zr[tid][0] + Zr[tid][1];
        if (ib != jb)
            Zpart[(ns * 16 + ib) * LL + jb * 128 + tid] = Zc[tid][0] + Zc[tid][1];
    }
}

// ---------------------------------------------------------------------------
// Kernel 3: iZ[row] = 1 / sum of 16 per-tile partials
// ---------------------------------------------------------------------------
__global__ __launch_bounds__(256) void reduce_stats_kernel(
    const float* __restrict__ Zpart, float* __restrict__ iZfin)
{
    const int idx = blockIdx.x * 256 + threadIdx.x;   // ns*2048 + l
    const int ns = idx >> 11, l = idx & 2047;
    float Z = 0.f;
#pragma unroll
    for (int t = 0; t < 16; ++t) Z += Zpart[(ns * 16 + t) * LL + l];
    iZfin[idx] = 1.0f / Z;
}

// ---------------------------------------------------------------------------
// Kernel 4: recompute s (identical MFMA sequence), per-tile column partial
// sums of exp(s)*iZ_row for cols of BOTH blocks. Spart: [(ns*2048+m)*16+tile]
// ---------------------------------------------------------------------------
__global__ __launch_bounds__(256, 3) void colsum_kernel(
    const unsigned short* __restrict__ Ph, const unsigned short* __restrict__ Pl,
    const float* __restrict__ iZfin, float* __restrict__ Spart)
{
    __shared__ unsigned short pan[6][4096];                 // 48 KB panels
    __shared__ float Sr[128][2], Sc[128][2];                // 2 KB
    int pair, ns;  work_decode(blockIdx.x, blockIdx.y, pair, ns);
    int ib, jb;    pair_decode(pair, ib, jb);
    const int tid = threadIdx.x;
    const int lane = tid & 63, quad = lane >> 4, l16 = lane & 15, wave = tid >> 6;
    const int wr = wave >> 1, wc = wave & 1;

    float4v acc[4][4];
    mfma_core(Ph, Pl, ns, ib, jb, tid, pan, acc);

    float wrow[4][4];
#pragma unroll
    for (int rt = 0; rt < 4; ++rt)
#pragma unroll
        for (int rg = 0; rg < 4; ++rg)
            wrow[rt][rg] = iZfin[ns * LL + ib * 128 + wr * 64 + rt * 16 + quad * 4 + rg];
    float wcol[4];
#pragma unroll
    for (int ct = 0; ct < 4; ++ct)
        wcol[ct] = iZfin[ns * LL + jb * 128 + wc * 64 + ct * 16 + l16];

    float dsum[4] = {0.f, 0.f, 0.f, 0.f};
#pragma unroll
    for (int rt = 0; rt < 4; ++rt)
#pragma unroll
        for (int rg = 0; rg < 4; ++rg) {
            const int rl = wr * 64 + rt * 16 + quad * 4 + rg;
            float ts = 0.f;
#pragma unroll
            for (int ct = 0; ct < 4; ++ct) {
                float e = __expf(acc[rt][ct][rg] * SCALE);
                bool diag = (ib == jb) && (rl == wc * 64 + ct * 16 + l16);
                dsum[ct] += diag ? 0.f : e * wrow[rt][rg];
                ts += e * wcol[ct];
            }
            if (ib != jb) {
                ts += __shfl_xor(ts, 1);
                ts += __shfl_xor(ts, 2);
                ts += __shfl_xor(ts, 4);
                ts += __shfl_xor(ts, 8);
                if (l16 == 0) Sr[rl][wc] = ts;
            }
        }

#pragma unroll
    for (int ct = 0; ct < 4; ++ct) {
        float s = dsum[ct];
        s += __shfl_xor(s, 16);
        s += __shfl_xor(s, 32);
        if (quad == 0) Sc[wc * 64 + ct * 16 + l16][wr] = s;
    }
    __syncthreads();
    if (tid < 128) {
        Spart[((size_t)ns * LL + jb * 128 + tid) * 16 + ib] = Sc[tid][0] + Sc[tid][1];
        if (ib != jb)
            Spart[((size_t)ns * LL + ib * 128 + tid) * 16 + jb] = Sr[tid][0] + Sr[tid][1];
    }
}

// ---------------------------------------------------------------------------
// Kernel 5: score = fp64 sum of 16 tile partials; exact bottom-k mask via
// rank counting: mask[i] = #{j: score_j < score_i} < 1024
// ---------------------------------------------------------------------------
__global__ __launch_bounds__(1024) void mask_kernel(
    const float* __restrict__ Spart, unsigned char* __restrict__ maskbuf)
{
    __shared__ double s[LL];
    const int ns = blockIdx.x;
    const int half = blockIdx.y;
    const int tid = threadIdx.x;
#pragma unroll
    for (int h = 0; h < 2; ++h) {
        int m = tid + h * 1024;
        const float* sp = Spart + ((size_t)ns * LL + m) * 16;
        double a = 0.0;
#pragma unroll
        for (int t = 0; t < 16; ++t) a += (double)sp[t];
        s[m] = a;
    }
    __syncthreads();
    const int i = half * 1024 + tid;
    const double si = s[i];
    int cnt = 0;
    for (int j = 0; j < LL; ++j) cnt += (s[j] < si) ? 1 : 0;
    maskbuf[ns * LL + i] = (cnt < 1024) ? 1 : 0;
}

// ---------------------------------------------------------------------------
// Kernel 6: blend, all fp32.
// ---------------------------------------------------------------------------
__global__ __launch_bounds__(256) void blend_kernel(
    const float* __restrict__ xt, const float* __restrict__ xf,
    const unsigned char* __restrict__ maskbuf, float* __restrict__ out)
{
    const int idx4 = blockIdx.x * 256 + threadIdx.x;
    const size_t q = (size_t)idx4 * 4;
    const int row = (int)(q >> 7);
    const float4 a = *(const float4*)(xt + q);
    const float4 b = *(const float4*)(xf + q);
    const int mt = maskbuf[row] & 1;
    const int mf = maskbuf[16384 + row] & 1;
    const bool ct = mt && !mf;
    const bool cf = mf && !mt;
    float4 av;
    av.x = 0.5f * (a.x + b.x);  av.y = 0.5f * (a.y + b.y);
    av.z = 0.5f * (a.z + b.z);  av.w = 0.5f * (a.w + b.w);
    float4 o0 = ct ? av : a;
    float4 o1 = cf ? av : b;
    *(float4*)(out + q)                   = o0;
    *(float4*)(out + (size_t)2097152 + q) = o1;
}

// ---------------------------------------------------------------------------
extern "C" void kernel_launch(void* const* d_in, const int* in_sizes, int n_in,
                              void* d_out, int out_size, void* d_ws, size_t ws_size,
                              hipStream_t stream)
{
    const float* xt = (const float*)d_in[0];
    const float* xf = (const float*)d_in[1];
    const float* W  = (const float*)d_in[2];
    const float* b  = (const float*)d_in[3];
    float* out = (float*)d_out;

    // d_out (16.8 MB) holds P split: Ph bf16 [0,8.39MB), Pl bf16 [8.39,16.8MB).
    // Both dead before blend overwrites d_out.
    unsigned short* Ph = (unsigned short*)d_out;
    unsigned short* Pl = Ph + (size_t)NS * SLAB;

    float* Zpart = (float*)d_ws;                       // 16*16*2048 = 524288 f
    float* iZfin = Zpart + 16 * 16 * LL;               // 32768 f
    float* Spart = iZfin + NS * LL;                    // 524288 f
    unsigned char* maskbuf = (unsigned char*)(Spart + (size_t)16 * LL * 16);
    // total ws ~4.4 MB

    proj_kernel<<<dim3(32, NS), 256, 0, stream>>>(xt, xf, W, b, Ph, Pl);
    stats_kernel<<<dim3(NPAIR, NS), 256, 0, stream>>>(Ph, Pl, Zpart);
    reduce_stats_kernel<<<128, 256, 0, stream>>>(Zpart, iZfin);
    colsum_kernel<<<dim3(NPAIR, NS), 256, 0, stream>>>(Ph, Pl, iZfin, Spart);
    mask_kernel<<<dim3(NS, 2), 1024, 0, stream>>>(Spart, maskbuf);
    blend_kernel<<<2048, 256, 0, stream>>>(xt, xf, maskbuf, out);
}